// Round 8
// baseline (342.254 us; speedup 1.0000x reference)
//
#include <hip/hip_runtime.h>
#include <hip/hip_bf16.h>
#include <stdint.h>

#define B_ 2
#define S_ 1024
#define H_ 16
#define D_ 128
#define HID 2048
#define POS_ 1024
#define L_ 2048
#define NQKV 6144

using f32x4  = __attribute__((ext_vector_type(4))) float;
using bf16x8 = __attribute__((ext_vector_type(8))) short;
using us4    = __attribute__((ext_vector_type(4))) unsigned short;
using us8    = __attribute__((ext_vector_type(8))) unsigned short;

typedef const __attribute__((address_space(1))) void* gp_t;
typedef __attribute__((address_space(3))) void* lp_t;

__device__ __forceinline__ unsigned short f2bf(float f){
  union { float f; uint32_t u; } v; v.f = f;
  uint32_t r = v.u + 0x7FFFu + ((v.u >> 16) & 1u);
  return (unsigned short)(r >> 16);
}
__device__ __forceinline__ float bf2f(unsigned short u){
  return __uint_as_float(((uint32_t)u) << 16);
}

__global__ void k_cvt(const float* __restrict__ s, unsigned short* __restrict__ d, int n){
  int i = (blockIdx.x * blockDim.x + threadIdx.x) * 4;
  if (i < n){
    float4 v = *(const float4*)(s + i);
    us4 o;
    o[0] = f2bf(v.x); o[1] = f2bf(v.y); o[2] = f2bf(v.z); o[3] = f2bf(v.w);
    *(us4*)(d + i) = o;
  }
}

// mask * log2e -> bf16 in FRAGMENT order: mf[par][qg(64)][tt(32)][lg(4)][lr(16)][nf*4+i]
// total slots = 2*64*32*4*16 = 262144; each thread writes 16 bf16 (32 B).
__global__ void k_mcvt(const float* __restrict__ mask, unsigned short* __restrict__ mf){
  int idx = blockIdx.x*256 + threadIdx.x;
  if (idx >= 262144) return;
  int lr = idx & 15, lg = (idx >> 4) & 3, tt = (idx >> 6) & 31;
  int qg = (idx >> 11) & 63, par = idx >> 17;
  const float LOG2E = 1.4426950408889634f;
  const float* src = mask + (size_t)par*4194304 + 2097152;
  unsigned short o[16];
  #pragma unroll
  for (int nf=0; nf<4; ++nf)
    #pragma unroll
    for (int i=0; i<4; ++i){
      int q = qg*16 + lg*4 + i;
      int t = tt*64 + nf*16 + lr;
      o[nf*4+i] = f2bf(src[(size_t)q*2048 + t] * LOG2E);
    }
  us8* dst = (us8*)(mf + (size_t)idx*16);
  dst[0] = *(const us8*)&o[0];
  dst[1] = *(const us8*)&o[8];
}

__global__ void k_cache(const float* __restrict__ kc, unsigned short* __restrict__ kf){
  int i = (blockIdx.x * blockDim.x + threadIdx.x) * 4;
  if (i >= B_*POS_*H_*D_) return;
  int b = i >> 21;
  int rem = i & ((1 << 21) - 1);
  size_t src = (size_t)b * (2*POS_*H_*D_) + rem;
  size_t dst = (size_t)b * (L_*H_*D_) + rem;
  float4 k4 = *(const float4*)(kc + src);
  us4 ko;
  ko[0]=f2bf(k4.x); ko[1]=f2bf(k4.y); ko[2]=f2bf(k4.z); ko[3]=f2bf(k4.w);
  *(us4*)(kf + dst) = ko;
}

__global__ void k_rope(const float* __restrict__ qkv, const float* __restrict__ cosb,
    const float* __restrict__ sinb, float* __restrict__ kout, float* __restrict__ vout,
    unsigned short* __restrict__ qb, unsigned short* __restrict__ kf)
{
  int idx = blockIdx.x*blockDim.x + threadIdx.x;
  int j  = idx & 63;
  int hh = (idx >> 6) & 15;
  int s  = (idx >> 10) & 1023;
  int b  = idx >> 20;
  int m  = b*S_ + s;
  float c  = cosb[(POS_ + s)*64 + j];
  float sn = sinb[(POS_ + s)*64 + j];
  size_t base = (size_t)m*NQKV + hh*D_ + j;
  float q1 = qkv[base],          q2 = qkv[base + 64];
  float k1 = qkv[base + HID],    k2 = qkv[base + HID + 64];
  float v1 = qkv[base + 2*HID],  v2 = qkv[base + 2*HID + 64];
  float qr = c*q1 - sn*q2, qi = sn*q1 + c*q2;
  float kr = c*k1 - sn*k2, ki = sn*k1 + c*k2;
  const float SCQ = 0.12751743232994544f;   // (1/sqrt(128)) * log2e, folded into Q
  size_t o = (size_t)m*HID + hh*D_ + j;
  kout[o] = kr; kout[o + 64] = ki;
  vout[o] = v1; vout[o + 64] = v2;
  qb[o] = f2bf(qr*SCQ); qb[o + 64] = f2bf(qi*SCQ);
  size_t fo = ((size_t)(b*L_ + POS_ + s)*H_ + hh)*D_ + j;
  kf[fo] = f2bf(kr); kf[fo + 64] = f2bf(ki);
}

// Build V^T globally: vt[b][h][d][t], bf16.
__global__ __launch_bounds__(256) void k_vtrans(const float* __restrict__ vc,
    const float* __restrict__ qkv, unsigned short* __restrict__ vt)
{
  __shared__ unsigned short T[64*130];
  int blk = blockIdx.x;
  int tt = blk & 31, h = (blk >> 5) & 15, b = blk >> 9;
  int t0 = tt * 64;
  int tid = threadIdx.x;
  int d0 = (tid & 31) * 4, tr = tid >> 5;
  #pragma unroll
  for (int pass=0; pass<8; ++pass){
    int t = tr + pass*8;
    int gt = t0 + t;
    float4 v4;
    if (gt < POS_){
      v4 = *(const float4*)(vc + (((size_t)(b*2*POS_ + gt))*H_ + h)*D_ + d0);
    } else {
      v4 = *(const float4*)(qkv + (size_t)(b*S_ + gt - POS_)*NQKV + 2*HID + h*D_ + d0);
    }
    us4 o; o[0]=f2bf(v4.x); o[1]=f2bf(v4.y); o[2]=f2bf(v4.z); o[3]=f2bf(v4.w);
    *(us4*)(&T[t*130 + d0]) = o;
  }
  __syncthreads();
  int d = tid >> 1, th = (tid & 1) * 32;
  uint4 buf4[4];
  unsigned short* buf = (unsigned short*)buf4;
  #pragma unroll
  for (int e=0;e<32;++e) buf[e] = T[(th+e)*130 + d];
  unsigned short* dst = vt + (((size_t)(b*H_ + h)*D_ + d)*L_) + t0 + th;
  #pragma unroll
  for (int c=0;c<4;++c) *(uint4*)(dst + c*8) = buf4[c];
}

__global__ __launch_bounds__(256) void k_gemm(const unsigned short* __restrict__ A,
    const unsigned short* __restrict__ Bm, const float* __restrict__ bias,
    float* __restrict__ C, int Md, int Nd, int Kd)
{
  __shared__ unsigned short As[128*64];
  __shared__ unsigned short Bs[128*64];
  const int tid = threadIdx.x;
  const int lane = tid & 63, w = tid >> 6;
  const int wr = w >> 1, wc = w & 1;
  const int lg = lane >> 4, lr = lane & 15;
  const int tiles_n = Nd >> 7;
  const int tm = blockIdx.x / tiles_n, tn = blockIdx.x % tiles_n;
  f32x4 acc[4][4];
  #pragma unroll
  for (int i=0;i<4;++i)
    #pragma unroll
    for (int j=0;j<4;++j){ f32x4 z = {0.f,0.f,0.f,0.f}; acc[i][j] = z; }

  for (int k0 = 0; k0 < Kd; k0 += 64){
    #pragma unroll
    for (int j=0;j<4;++j){
      int chunk = j*256 + w*64 + lane;
      int row = chunk >> 3, cc = chunk & 7;
      int ccs = cc ^ (row & 7);
      const unsigned short* ga = A  + (size_t)(tm*128 + row)*Kd + k0 + ccs*8;
      __builtin_amdgcn_global_load_lds((gp_t)ga,
          (lp_t)((char*)As + (j*256 + w*64)*16), 16, 0, 0);
      const unsigned short* gb = Bm + (size_t)(tn*128 + row)*Kd + k0 + ccs*8;
      __builtin_amdgcn_global_load_lds((gp_t)gb,
          (lp_t)((char*)Bs + (j*256 + w*64)*16), 16, 0, 0);
    }
    __syncthreads();
    #pragma unroll
    for (int ks=0; ks<2; ++ks){
      bf16x8 af[4], bf[4];
      #pragma unroll
      for (int mi=0;mi<4;++mi){
        int row = wr*64 + mi*16 + lr;
        int byte = (row*128 + ks*64 + lg*16) ^ ((row & 7) << 4);
        af[mi] = *(const bf16x8*)((const char*)As + byte);
      }
      #pragma unroll
      for (int ni=0;ni<4;++ni){
        int row = wc*64 + ni*16 + lr;
        int byte = (row*128 + ks*64 + lg*16) ^ ((row & 7) << 4);
        bf[ni] = *(const bf16x8*)((const char*)Bs + byte);
      }
      #pragma unroll
      for (int mi=0;mi<4;++mi)
        #pragma unroll
        for (int ni=0;ni<4;++ni)
          acc[mi][ni] = __builtin_amdgcn_mfma_f32_16x16x32_bf16(af[mi], bf[ni], acc[mi][ni], 0, 0, 0);
    }
    __syncthreads();
  }
  #pragma unroll
  for (int mi=0;mi<4;++mi)
    #pragma unroll
    for (int ni=0;ni<4;++ni){
      int col = tn*128 + wc*64 + ni*16 + lr;
      float bv = bias[col];
      #pragma unroll
      for (int i=0;i<4;++i){
        int row = tm*128 + wr*64 + mi*16 + lg*4 + i;
        C[(size_t)row*Nd + col] = acc[mi][ni][i] + bv;
      }
    }
}

union MU { us8 v[2]; unsigned short s[16]; };

// Flash attention over a half of the KV range; 2-phase double-buffered pipeline.
__global__ __launch_bounds__(256, 3) void k_attn_part(const unsigned short* __restrict__ Q,
    const unsigned short* __restrict__ Kf, const unsigned short* __restrict__ vt,
    const unsigned short* __restrict__ mf, float* __restrict__ Opart, float* __restrict__ ml)
{
  __shared__ unsigned short Kt[2][64*128];   // 16 KB each
  __shared__ unsigned short Vt[2][128*64];   // 16 KB each
  __shared__ unsigned short Pw[4][16*64];    // 8 KB
  const int tid = threadIdx.x;
  const int lane = tid & 63, w = tid >> 6;
  const int lg = lane >> 4, lr = lane & 15;
  const int bid = blockIdx.x;                 // split*512 + b*256 + h*16 + qblk
  const int qblk = bid & 15, h = (bid >> 4) & 15, b = (bid >> 8) & 1, split = bid >> 9;
  const int q0 = qblk * 64;
  const int tlo = split * (L_/2);

  bf16x8 qf[4];
  {
    const unsigned short* qbase = Q + ((size_t)(b*S_ + q0 + w*16 + lr))*HID + h*D_;
    #pragma unroll
    for (int ks=0; ks<4; ++ks)
      qf[ks] = *(const bf16x8*)(qbase + ks*32 + lg*8);
  }
  f32x4 oacc[8];
  #pragma unroll
  for (int i=0;i<8;++i){ f32x4 z = {0.f,0.f,0.f,0.f}; oacc[i] = z; }
  float m_i[4] = {-1e30f,-1e30f,-1e30f,-1e30f};
  float l_i[4] = {0.f,0.f,0.f,0.f};
  const unsigned short* vtb = vt + ((size_t)(b*H_ + h)*D_)*L_;
  const unsigned short* mfrag = mf
      + ((size_t)((h & 1)*64 + qblk*4 + w) * 32) * 1024
      + (size_t)(lg*16 + lr) * 16;

  auto stage = [&](int t0, int bufsel){
    #pragma unroll
    for (int j=0;j<4;++j){
      int chunk = j*256 + w*64 + lane;
      int row = chunk >> 4, cc = chunk & 15;
      int ccs = cc ^ (row & 7);
      const unsigned short* g = Kf + ((size_t)(b*L_ + t0 + row)*H_ + h)*D_ + ccs*8;
      __builtin_amdgcn_global_load_lds((gp_t)g,
          (lp_t)((char*)&Kt[0][0] + bufsel*16384 + (j*256 + w*64)*16), 16, 0, 0);
    }
    #pragma unroll
    for (int j=0;j<4;++j){
      int chunk = j*256 + w*64 + lane;
      int row = chunk >> 3, cc = chunk & 7;
      int ccs = cc ^ (row & 7);
      const unsigned short* g = vtb + (size_t)row*L_ + t0 + ccs*8;
      __builtin_amdgcn_global_load_lds((gp_t)g,
          (lp_t)((char*)&Vt[0][0] + bufsel*16384 + (j*256 + w*64)*16), 16, 0, 0);
    }
  };
  auto loadMask = [&](int t0, MU& mu){
    const us8* mv = (const us8*)(mfrag + (size_t)(t0 - tlo >> 6)*1024 + (size_t)(split ? 16384 : 0));
    mu.v[0] = mv[0]; mu.v[1] = mv[1];
  };
  auto compute = [&](int bufsel, const MU& mu){
    const char* kbase = (const char*)&Kt[0][0] + bufsel*16384;
    const char* vbase = (const char*)&Vt[0][0] + bufsel*16384;
    f32x4 sc[4];
    #pragma unroll
    for (int nf=0;nf<4;++nf){
      f32x4 a = {0.f,0.f,0.f,0.f};
      #pragma unroll
      for (int ks=0;ks<4;++ks){
        int row = nf*16 + lr;
        int byte = (row*256 + ks*64 + lg*16) ^ ((row & 7) << 4);
        bf16x8 kb = *(const bf16x8*)(kbase + byte);
        a = __builtin_amdgcn_mfma_f32_16x16x32_bf16(qf[ks], kb, a, 0, 0, 0);
      }
      sc[nf] = a;
    }
    float sv[4][4];
    float tmax[4] = {-1e30f,-1e30f,-1e30f,-1e30f};
    #pragma unroll
    for (int nf=0;nf<4;++nf)
      #pragma unroll
      for (int i=0;i<4;++i){
        float v = sc[nf][i] + bf2f(mu.s[nf*4+i]);
        sv[nf][i] = v;
        tmax[i] = fmaxf(tmax[i], v);
      }
    #pragma unroll
    for (int i=0;i<4;++i){
      tmax[i] = fmaxf(tmax[i], __shfl_xor(tmax[i], 1));
      tmax[i] = fmaxf(tmax[i], __shfl_xor(tmax[i], 2));
      tmax[i] = fmaxf(tmax[i], __shfl_xor(tmax[i], 4));
      tmax[i] = fmaxf(tmax[i], __shfl_xor(tmax[i], 8));
    }
    float corr[4];
    #pragma unroll
    for (int i=0;i<4;++i){
      float mn = fmaxf(m_i[i], tmax[i]);
      corr[i] = __builtin_amdgcn_exp2f(m_i[i] - mn);
      m_i[i] = mn;
    }
    float rs[4] = {0.f,0.f,0.f,0.f};
    float pp[4][4];
    #pragma unroll
    for (int nf=0;nf<4;++nf)
      #pragma unroll
      for (int i=0;i<4;++i){
        float p = __builtin_amdgcn_exp2f(sv[nf][i] - m_i[i]);
        pp[nf][i] = p;
        rs[i] += p;
      }
    #pragma unroll
    for (int i=0;i<4;++i){
      rs[i] += __shfl_xor(rs[i], 1);
      rs[i] += __shfl_xor(rs[i], 2);
      rs[i] += __shfl_xor(rs[i], 4);
      rs[i] += __shfl_xor(rs[i], 8);
      l_i[i] = l_i[i]*corr[i] + rs[i];
    }
    #pragma unroll
    for (int df=0;df<8;++df)
      #pragma unroll
      for (int i=0;i<4;++i) oacc[df][i] *= corr[i];

    #pragma unroll
    for (int nf=0;nf<4;++nf)
      #pragma unroll
      for (int i=0;i<4;++i){
        int row = lg*4 + i;
        int byte = (row*128 + nf*32 + lr*2) ^ ((row & 7) << 4);
        *(unsigned short*)((char*)(&Pw[w][0]) + byte) = f2bf(pp[nf][i]);
      }
    __asm__ volatile("s_waitcnt lgkmcnt(0)" ::: "memory");
    #pragma unroll
    for (int ks2=0; ks2<2; ++ks2){
      int pbyte = (lr*128 + ks2*64 + lg*16) ^ ((lr & 7) << 4);
      bf16x8 pa = *(const bf16x8*)((const char*)(&Pw[w][0]) + pbyte);
      #pragma unroll
      for (int df=0;df<8;++df){
        int vrow = df*16 + lr;
        int vbyte = (vrow*128 + ks2*64 + lg*16) ^ ((vrow & 7) << 4);
        bf16x8 vb = *(const bf16x8*)(vbase + vbyte);
        oacc[df] = __builtin_amdgcn_mfma_f32_16x16x32_bf16(pa, vb, oacc[df], 0, 0, 0);
      }
    }
  };

  MU muA, muB;
  // prologue: stage tile 0 into buf 0
  stage(tlo, 0);
  loadMask(tlo, muA);
  __asm__ volatile("s_waitcnt vmcnt(0)" ::: "memory");
  __builtin_amdgcn_s_barrier();

  for (int tof = 0; tof < L_/2; tof += 128){
    // phase A: prefetch t+64 into buf1, compute buf0
    stage(tlo + tof + 64, 1);
    loadMask(tlo + tof + 64, muB);
    compute(0, muA);
    __asm__ volatile("s_waitcnt vmcnt(0)" ::: "memory");
    __builtin_amdgcn_s_barrier();
    // phase B: prefetch t+128 into buf0 (dummy refetch of tile 0 on last iter), compute buf1
    int t2 = (tof + 128 < L_/2) ? (tlo + tof + 128) : tlo;
    stage(t2, 0);
    loadMask(t2, muA);
    compute(1, muB);
    __asm__ volatile("s_waitcnt vmcnt(0)" ::: "memory");
    __builtin_amdgcn_s_barrier();
  }

  size_t rbase = (size_t)(b*H_ + h)*S_ + q0 + w*16;
  size_t pbase = (size_t)split*(B_*H_*S_) + rbase;
  #pragma unroll
  for (int df=0;df<8;++df)
    #pragma unroll
    for (int i=0;i<4;++i)
      Opart[(pbase + lg*4 + i)*D_ + df*16 + lr] = oacc[df][i];
  if (lr == 0){
    #pragma unroll
    for (int i=0;i<4;++i){
      size_t row = pbase + lg*4 + i;
      ml[row*2]     = m_i[i];
      ml[row*2 + 1] = l_i[i];
    }
  }
}

// Combine 2 splits: out = (w0*O0 + w1*O1) / (w0*l0 + w1*l1), weights exp2(m - M).
__global__ void k_comb(const float* __restrict__ Opart, const float* __restrict__ ml,
                       unsigned short* __restrict__ Ob)
{
  const int NR = B_*H_*S_;   // 32768 rows
  int idx = blockIdx.x*256 + threadIdx.x;       // NR*32 threads, 4 elems each
  int r = idx >> 5, dq = (idx & 31) * 4;
  float m0 = ml[(size_t)r*2],          l0 = ml[(size_t)r*2 + 1];
  float m1 = ml[(size_t)(NR + r)*2],   l1 = ml[(size_t)(NR + r)*2 + 1];
  float M  = fmaxf(m0, m1);
  float w0 = __builtin_amdgcn_exp2f(m0 - M);
  float w1 = __builtin_amdgcn_exp2f(m1 - M);
  float inv = 1.0f / (w0*l0 + w1*l1);
  float4 o0 = *(const float4*)(Opart + (size_t)r*D_ + dq);
  float4 o1 = *(const float4*)(Opart + (size_t)(NR + r)*D_ + dq);
  int s = r & (S_-1), bh = r >> 10;
  int b = bh >> 4, h = bh & 15;
  size_t o = ((size_t)(b*S_ + s))*HID + h*D_ + dq;
  us4 w;
  w[0] = f2bf((w0*o0.x + w1*o1.x)*inv);
  w[1] = f2bf((w0*o0.y + w1*o1.y)*inv);
  w[2] = f2bf((w0*o0.z + w1*o1.z)*inv);
  w[3] = f2bf((w0*o0.w + w1*o1.w)*inv);
  *(us4*)(Ob + o) = w;
}

extern "C" void kernel_launch(void* const* d_in, const int* in_sizes, int n_in,
                              void* d_out, int out_size, void* d_ws, size_t ws_size,
                              hipStream_t stream){
  const float* x    = (const float*)d_in[0];
  const float* mask = (const float*)d_in[1];
  const float* cosb = (const float*)d_in[2];
  const float* sinb = (const float*)d_in[3];
  const float* kc   = (const float*)d_in[4];
  const float* vc   = (const float*)d_in[5];
  const float* Wq   = (const float*)d_in[8];
  const float* bq   = (const float*)d_in[9];
  const float* Wk   = (const float*)d_in[10];
  const float* bk   = (const float*)d_in[11];
  const float* Wv   = (const float*)d_in[12];
  const float* bv   = (const float*)d_in[13];
  const float* Wo   = (const float*)d_in[14];
  const float* bo   = (const float*)d_in[15];

  float* out  = (float*)d_out;
  float* kout = out + 4194304;
  float* vout = out + 8388608;

  char* ws = (char*)d_ws;
  float*          qkv   = (float*)(ws);                      // 50331648 B (dead after rope/vtrans)
  float*          Opart = (float*)(ws);                      // 33554432 B, overlays dead qkv
  float*          ml    = (float*)(ws + 33554432);           // 524288 B
  unsigned short* xb    = (unsigned short*)(ws + 50331648);  // 8388608
  unsigned short* Wqkvb = (unsigned short*)(ws + 58720256);  // 25165824 (dead after QKV GEMM)
  unsigned short* mf    = (unsigned short*)(ws + 58720256);  // 8388608, overlays Wqkvb
  unsigned short* Wob   = (unsigned short*)(ws + 83886080);  // 8388608
  float*          bqkv  = (float*)(ws + 92274688);           // 24576
  unsigned short* qb    = (unsigned short*)(ws + 92299264);  // 8388608
  unsigned short* kf    = (unsigned short*)(ws + 100687872); // 16777216
  unsigned short* vt    = (unsigned short*)(ws + 117465088); // 16777216
  unsigned short* attnb = (unsigned short*)(ws + 134242304); // 8388608

  hipMemcpyAsync(bqkv,        bq, 2048*sizeof(float), hipMemcpyDeviceToDevice, stream);
  hipMemcpyAsync(bqkv + 2048, bk, 2048*sizeof(float), hipMemcpyDeviceToDevice, stream);
  hipMemcpyAsync(bqkv + 4096, bv, 2048*sizeof(float), hipMemcpyDeviceToDevice, stream);

  k_cvt<<<4096, 256, 0, stream>>>(x,  xb, 4194304);
  k_cvt<<<4096, 256, 0, stream>>>(Wq, Wqkvb,            4194304);
  k_cvt<<<4096, 256, 0, stream>>>(Wk, Wqkvb + 4194304,  4194304);
  k_cvt<<<4096, 256, 0, stream>>>(Wv, Wqkvb + 8388608,  4194304);
  k_cvt<<<4096, 256, 0, stream>>>(Wo, Wob, 4194304);
  k_cache<<<4096, 256, 0, stream>>>(kc, kf);

  k_gemm<<<16*48, 256, 0, stream>>>(xb, Wqkvb, bqkv, qkv, 2048, 6144, 2048);
  k_mcvt<<<1024, 256, 0, stream>>>(mask, mf);
  k_rope<<<8192, 256, 0, stream>>>(qkv, cosb, sinb, kout, vout, qb, kf);
  k_vtrans<<<1024, 256, 0, stream>>>(vc, qkv, vt);
  k_attn_part<<<1024, 256, 0, stream>>>(qb, kf, vt, mf, Opart, ml);
  k_comb<<<4096, 256, 0, stream>>>(Opart, ml, attnb);
  k_gemm<<<16*16, 256, 0, stream>>>(attnb, Wob, bo, out, 2048, 2048, 2048);

  (void)in_sizes; (void)n_in; (void)out_size; (void)ws_size;
}

// Round 9
// 335.148 us; speedup vs baseline: 1.0212x; 1.0212x over previous
//
#include <hip/hip_runtime.h>
#include <hip/hip_bf16.h>
#include <stdint.h>

#define B_ 2
#define S_ 1024
#define H_ 16
#define D_ 128
#define HID 2048
#define POS_ 1024
#define L_ 2048
#define NQKV 6144

using f32x4  = __attribute__((ext_vector_type(4))) float;
using bf16x8 = __attribute__((ext_vector_type(8))) short;
using us4    = __attribute__((ext_vector_type(4))) unsigned short;
using us8    = __attribute__((ext_vector_type(8))) unsigned short;

typedef const __attribute__((address_space(1))) void* gp_t;
typedef __attribute__((address_space(3))) void* lp_t;

__device__ __forceinline__ unsigned short f2bf(float f){
  union { float f; uint32_t u; } v; v.f = f;
  uint32_t r = v.u + 0x7FFFu + ((v.u >> 16) & 1u);
  return (unsigned short)(r >> 16);
}
__device__ __forceinline__ float bf2f(unsigned short u){
  return __uint_as_float(((uint32_t)u) << 16);
}

__global__ void k_cvt(const float* __restrict__ s, unsigned short* __restrict__ d, int n){
  int i = (blockIdx.x * blockDim.x + threadIdx.x) * 4;
  if (i < n){
    float4 v = *(const float4*)(s + i);
    us4 o;
    o[0] = f2bf(v.x); o[1] = f2bf(v.y); o[2] = f2bf(v.z); o[3] = f2bf(v.w);
    *(us4*)(d + i) = o;
  }
}

// mask * log2e -> bf16 in FRAGMENT order: mf[par][qg(64)][tt(32)][lg(4)][lr(16)][nf*4+i]
// total slots = 2*64*32*4*16 = 262144; each thread writes 16 bf16 (32 B).
__global__ void k_mcvt(const float* __restrict__ mask, unsigned short* __restrict__ mf){
  int idx = blockIdx.x*256 + threadIdx.x;
  if (idx >= 262144) return;
  int lr = idx & 15, lg = (idx >> 4) & 3, tt = (idx >> 6) & 31;
  int qg = (idx >> 11) & 63, par = idx >> 17;
  const float LOG2E = 1.4426950408889634f;
  const float* src = mask + (size_t)par*4194304 + 2097152;
  unsigned short o[16];
  #pragma unroll
  for (int nf=0; nf<4; ++nf)
    #pragma unroll
    for (int i=0; i<4; ++i){
      int q = qg*16 + lg*4 + i;
      int t = tt*64 + nf*16 + lr;
      o[nf*4+i] = f2bf(src[(size_t)q*2048 + t] * LOG2E);
    }
  us8* dst = (us8*)(mf + (size_t)idx*16);
  dst[0] = *(const us8*)&o[0];
  dst[1] = *(const us8*)&o[8];
}

__global__ void k_cache(const float* __restrict__ kc, unsigned short* __restrict__ kf){
  int i = (blockIdx.x * blockDim.x + threadIdx.x) * 4;
  if (i >= B_*POS_*H_*D_) return;
  int b = i >> 21;
  int rem = i & ((1 << 21) - 1);
  size_t src = (size_t)b * (2*POS_*H_*D_) + rem;
  size_t dst = (size_t)b * (L_*H_*D_) + rem;
  float4 k4 = *(const float4*)(kc + src);
  us4 ko;
  ko[0]=f2bf(k4.x); ko[1]=f2bf(k4.y); ko[2]=f2bf(k4.z); ko[3]=f2bf(k4.w);
  *(us4*)(kf + dst) = ko;
}

__global__ void k_rope(const float* __restrict__ qkv, const float* __restrict__ cosb,
    const float* __restrict__ sinb, float* __restrict__ kout, float* __restrict__ vout,
    unsigned short* __restrict__ qb, unsigned short* __restrict__ kf)
{
  int idx = blockIdx.x*blockDim.x + threadIdx.x;
  int j  = idx & 63;
  int hh = (idx >> 6) & 15;
  int s  = (idx >> 10) & 1023;
  int b  = idx >> 20;
  int m  = b*S_ + s;
  float c  = cosb[(POS_ + s)*64 + j];
  float sn = sinb[(POS_ + s)*64 + j];
  size_t base = (size_t)m*NQKV + hh*D_ + j;
  float q1 = qkv[base],          q2 = qkv[base + 64];
  float k1 = qkv[base + HID],    k2 = qkv[base + HID + 64];
  float v1 = qkv[base + 2*HID],  v2 = qkv[base + 2*HID + 64];
  float qr = c*q1 - sn*q2, qi = sn*q1 + c*q2;
  float kr = c*k1 - sn*k2, ki = sn*k1 + c*k2;
  const float SCQ = 0.12751743232994544f;   // (1/sqrt(128)) * log2e, folded into Q
  size_t o = (size_t)m*HID + hh*D_ + j;
  kout[o] = kr; kout[o + 64] = ki;
  vout[o] = v1; vout[o + 64] = v2;
  qb[o] = f2bf(qr*SCQ); qb[o + 64] = f2bf(qi*SCQ);
  size_t fo = ((size_t)(b*L_ + POS_ + s)*H_ + hh)*D_ + j;
  kf[fo] = f2bf(kr); kf[fo + 64] = f2bf(ki);
}

// Build V^T globally: vt[b][h][d][t], bf16.
__global__ __launch_bounds__(256) void k_vtrans(const float* __restrict__ vc,
    const float* __restrict__ qkv, unsigned short* __restrict__ vt)
{
  __shared__ unsigned short T[64*130];
  int blk = blockIdx.x;
  int tt = blk & 31, h = (blk >> 5) & 15, b = blk >> 9;
  int t0 = tt * 64;
  int tid = threadIdx.x;
  int d0 = (tid & 31) * 4, tr = tid >> 5;
  #pragma unroll
  for (int pass=0; pass<8; ++pass){
    int t = tr + pass*8;
    int gt = t0 + t;
    float4 v4;
    if (gt < POS_){
      v4 = *(const float4*)(vc + (((size_t)(b*2*POS_ + gt))*H_ + h)*D_ + d0);
    } else {
      v4 = *(const float4*)(qkv + (size_t)(b*S_ + gt - POS_)*NQKV + 2*HID + h*D_ + d0);
    }
    us4 o; o[0]=f2bf(v4.x); o[1]=f2bf(v4.y); o[2]=f2bf(v4.z); o[3]=f2bf(v4.w);
    *(us4*)(&T[t*130 + d0]) = o;
  }
  __syncthreads();
  int d = tid >> 1, th = (tid & 1) * 32;
  uint4 buf4[4];
  unsigned short* buf = (unsigned short*)buf4;
  #pragma unroll
  for (int e=0;e<32;++e) buf[e] = T[(th+e)*130 + d];
  unsigned short* dst = vt + (((size_t)(b*H_ + h)*D_ + d)*L_) + t0 + th;
  #pragma unroll
  for (int c=0;c<4;++c) *(uint4*)(dst + c*8) = buf4[c];
}

__global__ __launch_bounds__(256) void k_gemm(const unsigned short* __restrict__ A,
    const unsigned short* __restrict__ Bm, const float* __restrict__ bias,
    float* __restrict__ C, int Md, int Nd, int Kd)
{
  __shared__ unsigned short As[128*64];
  __shared__ unsigned short Bs[128*64];
  const int tid = threadIdx.x;
  const int lane = tid & 63, w = tid >> 6;
  const int wr = w >> 1, wc = w & 1;
  const int lg = lane >> 4, lr = lane & 15;
  const int tiles_n = Nd >> 7;
  const int tm = blockIdx.x / tiles_n, tn = blockIdx.x % tiles_n;
  f32x4 acc[4][4];
  #pragma unroll
  for (int i=0;i<4;++i)
    #pragma unroll
    for (int j=0;j<4;++j){ f32x4 z = {0.f,0.f,0.f,0.f}; acc[i][j] = z; }

  for (int k0 = 0; k0 < Kd; k0 += 64){
    #pragma unroll
    for (int j=0;j<4;++j){
      int chunk = j*256 + w*64 + lane;
      int row = chunk >> 3, cc = chunk & 7;
      int ccs = cc ^ (row & 7);
      const unsigned short* ga = A  + (size_t)(tm*128 + row)*Kd + k0 + ccs*8;
      __builtin_amdgcn_global_load_lds((gp_t)ga,
          (lp_t)((char*)As + (j*256 + w*64)*16), 16, 0, 0);
      const unsigned short* gb = Bm + (size_t)(tn*128 + row)*Kd + k0 + ccs*8;
      __builtin_amdgcn_global_load_lds((gp_t)gb,
          (lp_t)((char*)Bs + (j*256 + w*64)*16), 16, 0, 0);
    }
    __syncthreads();
    #pragma unroll
    for (int ks=0; ks<2; ++ks){
      bf16x8 af[4], bf[4];
      #pragma unroll
      for (int mi=0;mi<4;++mi){
        int row = wr*64 + mi*16 + lr;
        int byte = (row*128 + ks*64 + lg*16) ^ ((row & 7) << 4);
        af[mi] = *(const bf16x8*)((const char*)As + byte);
      }
      #pragma unroll
      for (int ni=0;ni<4;++ni){
        int row = wc*64 + ni*16 + lr;
        int byte = (row*128 + ks*64 + lg*16) ^ ((row & 7) << 4);
        bf[ni] = *(const bf16x8*)((const char*)Bs + byte);
      }
      #pragma unroll
      for (int mi=0;mi<4;++mi)
        #pragma unroll
        for (int ni=0;ni<4;++ni)
          acc[mi][ni] = __builtin_amdgcn_mfma_f32_16x16x32_bf16(af[mi], bf[ni], acc[mi][ni], 0, 0, 0);
    }
    __syncthreads();
  }
  #pragma unroll
  for (int mi=0;mi<4;++mi)
    #pragma unroll
    for (int ni=0;ni<4;++ni){
      int col = tn*128 + wc*64 + ni*16 + lr;
      float bv = bias[col];
      #pragma unroll
      for (int i=0;i<4;++i){
        int row = tm*128 + wr*64 + mi*16 + lg*4 + i;
        C[(size_t)row*Nd + col] = acc[mi][ni][i] + bv;
      }
    }
}

// Flash attention, KVBLK=32 double-buffered, iso-LDS with R7 (36 KB).
__global__ __launch_bounds__(256, 3) void k_attn_part(const unsigned short* __restrict__ Q,
    const unsigned short* __restrict__ Kf, const unsigned short* __restrict__ vt,
    const unsigned short* __restrict__ mf, float* __restrict__ Opart, float* __restrict__ ml)
{
  __shared__ unsigned short Kt[2][32*128];   // 8 KB each, [t][d] swizzled
  __shared__ unsigned short Vt[2][128*32];   // 8 KB each, [d][t] swizzled (64B rows)
  __shared__ unsigned short Pw[4][16*32];    // 4 KB, per-wave P tile
  const int tid = threadIdx.x;
  const int lane = tid & 63, w = tid >> 6;
  const int lg = lane >> 4, lr = lane & 15;
  // XCD-aware decode: hw round-robin (bid%8 = XCD). Give each XCD 8 whole
  // (split,b,h) groups (16 qblks each) -> per-XCD K/V working set 4 MB = L2.
  const int hw = blockIdx.x;
  const int xcd = hw & 7, slot = hw >> 3;
  const int g = xcd*8 + (slot >> 4);         // 0..63
  const int qblk = slot & 15;
  const int h = g & 15, b = (g >> 4) & 1, split = g >> 5;
  const int q0 = qblk * 64;
  const int tlo = split * (L_/2);

  bf16x8 qf[4];
  {
    const unsigned short* qbase = Q + ((size_t)(b*S_ + q0 + w*16 + lr))*HID + h*D_;
    #pragma unroll
    for (int ks=0; ks<4; ++ks)
      qf[ks] = *(const bf16x8*)(qbase + ks*32 + lg*8);
  }
  f32x4 oacc[8];
  #pragma unroll
  for (int i=0;i<8;++i){ f32x4 z = {0.f,0.f,0.f,0.f}; oacc[i] = z; }
  float m_i[4] = {-1e30f,-1e30f,-1e30f,-1e30f};
  float l_i[4] = {0.f,0.f,0.f,0.f};
  const unsigned short* vtb = vt + ((size_t)(b*H_ + h)*D_)*L_;
  const unsigned short* mfrag = mf
      + ((size_t)((h & 1)*64 + qblk*4 + w) * 32) * 1024
      + (size_t)(lg*16 + lr) * 16;

  // stage a 32-t tile (K: [32][128]; V^T: [128][32]) with read-side XOR baked
  // into the global source (gload_lds dest is linear).
  auto stage = [&](int t0, int bufsel){
    #pragma unroll
    for (int j=0;j<2;++j){
      int chunk = j*256 + tid;               // 512 chunks, 16/row
      int row = chunk >> 4, cc = chunk & 15;
      int ccs = cc ^ (row & 7);
      const unsigned short* gk = Kf + ((size_t)(b*L_ + t0 + row)*H_ + h)*D_ + ccs*8;
      __builtin_amdgcn_global_load_lds((gp_t)gk,
          (lp_t)((char*)&Kt[0][0] + bufsel*8192 + chunk*16), 16, 0, 0);
    }
    #pragma unroll
    for (int j=0;j<2;++j){
      int chunk = j*256 + tid;               // 512 chunks, 4/row (64B rows)
      int rowp = chunk >> 2, ccp = chunk & 3;
      int sr = rowp ^ ((rowp >> 2) & 1);     // inverse of read-side bit6 flip
      int tc = ccp ^ (sr & 3);               // inverse of read-side bits4-5
      const unsigned short* gv = vtb + (size_t)sr*L_ + t0 + tc*8;
      __builtin_amdgcn_global_load_lds((gp_t)gv,
          (lp_t)((char*)&Vt[0][0] + bufsel*8192 + chunk*16), 16, 0, 0);
    }
  };
  auto loadMask = [&](int t0)->us8{          // t0 global; one us8 per 32-tile
    const us8* mv = (const us8*)(mfrag + (size_t)(t0 >> 6)*1024);
    return mv[(t0 >> 5) & 1];
  };
  auto compute = [&](int bufsel, us8 mu){
    const char* kbase = (const char*)&Kt[0][0] + bufsel*8192;
    const char* vbase = (const char*)&Vt[0][0] + bufsel*8192;
    f32x4 sc[2];
    #pragma unroll
    for (int nf=0;nf<2;++nf){
      f32x4 a = {0.f,0.f,0.f,0.f};
      #pragma unroll
      for (int ks=0;ks<4;++ks){
        int row = nf*16 + lr;
        int byte = (row*256 + ks*64 + lg*16) ^ ((row & 7) << 4);
        bf16x8 kb = *(const bf16x8*)(kbase + byte);
        a = __builtin_amdgcn_mfma_f32_16x16x32_bf16(qf[ks], kb, a, 0, 0, 0);
      }
      sc[nf] = a;
    }
    float sv[2][4];
    float tmax[4] = {-1e30f,-1e30f,-1e30f,-1e30f};
    #pragma unroll
    for (int nf=0;nf<2;++nf)
      #pragma unroll
      for (int i=0;i<4;++i){
        float v = sc[nf][i] + bf2f(mu[nf*4+i]);
        sv[nf][i] = v;
        tmax[i] = fmaxf(tmax[i], v);
      }
    #pragma unroll
    for (int i=0;i<4;++i){
      tmax[i] = fmaxf(tmax[i], __shfl_xor(tmax[i], 1));
      tmax[i] = fmaxf(tmax[i], __shfl_xor(tmax[i], 2));
      tmax[i] = fmaxf(tmax[i], __shfl_xor(tmax[i], 4));
      tmax[i] = fmaxf(tmax[i], __shfl_xor(tmax[i], 8));
    }
    float corr[4];
    #pragma unroll
    for (int i=0;i<4;++i){
      float mn = fmaxf(m_i[i], tmax[i]);
      corr[i] = __builtin_amdgcn_exp2f(m_i[i] - mn);
      m_i[i] = mn;
    }
    float rs[4] = {0.f,0.f,0.f,0.f};
    float pp[2][4];
    #pragma unroll
    for (int nf=0;nf<2;++nf)
      #pragma unroll
      for (int i=0;i<4;++i){
        float p = __builtin_amdgcn_exp2f(sv[nf][i] - m_i[i]);
        pp[nf][i] = p;
        rs[i] += p;
      }
    #pragma unroll
    for (int i=0;i<4;++i){
      rs[i] += __shfl_xor(rs[i], 1);
      rs[i] += __shfl_xor(rs[i], 2);
      rs[i] += __shfl_xor(rs[i], 4);
      rs[i] += __shfl_xor(rs[i], 8);
      l_i[i] = l_i[i]*corr[i] + rs[i];
    }
    #pragma unroll
    for (int df=0;df<8;++df)
      #pragma unroll
      for (int i=0;i<4;++i) oacc[df][i] *= corr[i];

    // P (D-layout) -> per-wave LDS (A-layout source), swizzled both sides
    #pragma unroll
    for (int nf=0;nf<2;++nf)
      #pragma unroll
      for (int i=0;i<4;++i){
        int row = lg*4 + i;
        int byte = (row*64 + (nf*16+lr)*2) ^ ((row & 7) << 4);
        *(unsigned short*)((char*)(&Pw[w][0]) + byte) = f2bf(pp[nf][i]);
      }
    __asm__ volatile("s_waitcnt lgkmcnt(0)" ::: "memory");
    int pbyte = (lr*64 + lg*16) ^ ((lr & 7) << 4);
    bf16x8 pa = *(const bf16x8*)((const char*)(&Pw[w][0]) + pbyte);
    #pragma unroll
    for (int df=0;df<8;++df){
      int vrow = df*16 + lr;
      int vbyte = (vrow*64 + lg*16) ^ ((vrow & 7) << 4);
      bf16x8 vb = *(const bf16x8*)(vbase + vbyte);
      oacc[df] = __builtin_amdgcn_mfma_f32_16x16x32_bf16(pa, vb, oacc[df], 0, 0, 0);
    }
  };

  // prologue
  stage(tlo, 0);
  us8 muA = loadMask(tlo), muB;
  __asm__ volatile("s_waitcnt vmcnt(0)" ::: "memory");
  __builtin_amdgcn_s_barrier();

  for (int tof = 0; tof < L_/2; tof += 64){
    stage(tlo + tof + 32, 1);                 // prefetch into buf1
    muB = loadMask(tlo + tof + 32);
    compute(0, muA);                          // compute buf0 (stage in flight)
    __asm__ volatile("s_waitcnt vmcnt(0)" ::: "memory");
    __builtin_amdgcn_s_barrier();
    int t2 = (tof + 64 < L_/2) ? (tlo + tof + 64) : tlo;   // dummy on last
    stage(t2, 0);
    muA = loadMask(t2);
    compute(1, muB);
    __asm__ volatile("s_waitcnt vmcnt(0)" ::: "memory");
    __builtin_amdgcn_s_barrier();
  }

  size_t rbase = (size_t)(b*H_ + h)*S_ + q0 + w*16;
  size_t pbase = (size_t)split*(B_*H_*S_) + rbase;
  #pragma unroll
  for (int df=0;df<8;++df)
    #pragma unroll
    for (int i=0;i<4;++i)
      Opart[(pbase + lg*4 + i)*D_ + df*16 + lr] = oacc[df][i];
  if (lr == 0){
    #pragma unroll
    for (int i=0;i<4;++i){
      size_t row = pbase + lg*4 + i;
      ml[row*2]     = m_i[i];
      ml[row*2 + 1] = l_i[i];
    }
  }
}

// Combine 2 splits: out = (w0*O0 + w1*O1) / (w0*l0 + w1*l1), weights exp2(m - M).
__global__ void k_comb(const float* __restrict__ Opart, const float* __restrict__ ml,
                       unsigned short* __restrict__ Ob)
{
  const int NR = B_*H_*S_;   // 32768 rows
  int idx = blockIdx.x*256 + threadIdx.x;       // NR*32 threads, 4 elems each
  int r = idx >> 5, dq = (idx & 31) * 4;
  float m0 = ml[(size_t)r*2],          l0 = ml[(size_t)r*2 + 1];
  float m1 = ml[(size_t)(NR + r)*2],   l1 = ml[(size_t)(NR + r)*2 + 1];
  float M  = fmaxf(m0, m1);
  float w0 = __builtin_amdgcn_exp2f(m0 - M);
  float w1 = __builtin_amdgcn_exp2f(m1 - M);
  float inv = 1.0f / (w0*l0 + w1*l1);
  float4 o0 = *(const float4*)(Opart + (size_t)r*D_ + dq);
  float4 o1 = *(const float4*)(Opart + (size_t)(NR + r)*D_ + dq);
  int s = r & (S_-1), bh = r >> 10;
  int b = bh >> 4, h = bh & 15;
  size_t o = ((size_t)(b*S_ + s))*HID + h*D_ + dq;
  us4 w;
  w[0] = f2bf((w0*o0.x + w1*o1.x)*inv);
  w[1] = f2bf((w0*o0.y + w1*o1.y)*inv);
  w[2] = f2bf((w0*o0.z + w1*o1.z)*inv);
  w[3] = f2bf((w0*o0.w + w1*o1.w)*inv);
  *(us4*)(Ob + o) = w;
}

extern "C" void kernel_launch(void* const* d_in, const int* in_sizes, int n_in,
                              void* d_out, int out_size, void* d_ws, size_t ws_size,
                              hipStream_t stream){
  const float* x    = (const float*)d_in[0];
  const float* mask = (const float*)d_in[1];
  const float* cosb = (const float*)d_in[2];
  const float* sinb = (const float*)d_in[3];
  const float* kc   = (const float*)d_in[4];
  const float* vc   = (const float*)d_in[5];
  const float* Wq   = (const float*)d_in[8];
  const float* bq   = (const float*)d_in[9];
  const float* Wk   = (const float*)d_in[10];
  const float* bk   = (const float*)d_in[11];
  const float* Wv   = (const float*)d_in[12];
  const float* bv   = (const float*)d_in[13];
  const float* Wo   = (const float*)d_in[14];
  const float* bo   = (const float*)d_in[15];

  float* out  = (float*)d_out;
  float* kout = out + 4194304;
  float* vout = out + 8388608;

  char* ws = (char*)d_ws;
  float*          qkv   = (float*)(ws);                      // 50331648 B (dead after rope/vtrans)
  float*          Opart = (float*)(ws);                      // 33554432 B, overlays dead qkv
  float*          ml    = (float*)(ws + 33554432);           // 524288 B
  unsigned short* xb    = (unsigned short*)(ws + 50331648);  // 8388608
  unsigned short* Wqkvb = (unsigned short*)(ws + 58720256);  // 25165824 (dead after QKV GEMM)
  unsigned short* mf    = (unsigned short*)(ws + 58720256);  // 8388608, overlays Wqkvb
  unsigned short* Wob   = (unsigned short*)(ws + 83886080);  // 8388608
  float*          bqkv  = (float*)(ws + 92274688);           // 24576
  unsigned short* qb    = (unsigned short*)(ws + 92299264);  // 8388608
  unsigned short* kf    = (unsigned short*)(ws + 100687872); // 16777216
  unsigned short* vt    = (unsigned short*)(ws + 117465088); // 16777216
  unsigned short* attnb = (unsigned short*)(ws + 134242304); // 8388608

  hipMemcpyAsync(bqkv,        bq, 2048*sizeof(float), hipMemcpyDeviceToDevice, stream);
  hipMemcpyAsync(bqkv + 2048, bk, 2048*sizeof(float), hipMemcpyDeviceToDevice, stream);
  hipMemcpyAsync(bqkv + 4096, bv, 2048*sizeof(float), hipMemcpyDeviceToDevice, stream);

  k_cvt<<<4096, 256, 0, stream>>>(x,  xb, 4194304);
  k_cvt<<<4096, 256, 0, stream>>>(Wq, Wqkvb,            4194304);
  k_cvt<<<4096, 256, 0, stream>>>(Wk, Wqkvb + 4194304,  4194304);
  k_cvt<<<4096, 256, 0, stream>>>(Wv, Wqkvb + 8388608,  4194304);
  k_cvt<<<4096, 256, 0, stream>>>(Wo, Wob, 4194304);
  k_cache<<<4096, 256, 0, stream>>>(kc, kf);

  k_gemm<<<16*48, 256, 0, stream>>>(xb, Wqkvb, bqkv, qkv, 2048, 6144, 2048);
  k_mcvt<<<1024, 256, 0, stream>>>(mask, mf);
  k_rope<<<8192, 256, 0, stream>>>(qkv, cosb, sinb, kout, vout, qb, kf);
  k_vtrans<<<1024, 256, 0, stream>>>(vc, qkv, vt);
  k_attn_part<<<1024, 256, 0, stream>>>(qb, kf, vt, mf, Opart, ml);
  k_comb<<<4096, 256, 0, stream>>>(Opart, ml, attnb);
  k_gemm<<<16*16, 256, 0, stream>>>(attnb, Wob, bo, out, 2048, 2048, 2048);

  (void)in_sizes; (void)n_in; (void)out_size; (void)ws_size;
}

// Round 10
// 274.833 us; speedup vs baseline: 1.2453x; 1.2195x over previous
//
#include <hip/hip_runtime.h>
#include <hip/hip_bf16.h>
#include <stdint.h>

#define B_ 2
#define S_ 1024
#define H_ 16
#define D_ 128
#define HID 2048
#define POS_ 1024
#define L_ 2048
#define NQKV 6144

using f32x4  = __attribute__((ext_vector_type(4))) float;
using bf16x8 = __attribute__((ext_vector_type(8))) short;
using us4    = __attribute__((ext_vector_type(4))) unsigned short;
using us8    = __attribute__((ext_vector_type(8))) unsigned short;

typedef const __attribute__((address_space(1))) void* gp_t;
typedef __attribute__((address_space(3))) void* lp_t;

__device__ __forceinline__ unsigned short f2bf(float f){
  union { float f; uint32_t u; } v; v.f = f;
  uint32_t r = v.u + 0x7FFFu + ((v.u >> 16) & 1u);
  return (unsigned short)(r >> 16);
}
__device__ __forceinline__ float bf2f(unsigned short u){
  return __uint_as_float(((uint32_t)u) << 16);
}

__global__ void k_cvt(const float* __restrict__ s, unsigned short* __restrict__ d, int n){
  int i = (blockIdx.x * blockDim.x + threadIdx.x) * 4;
  if (i < n){
    float4 v = *(const float4*)(s + i);
    us4 o;
    o[0] = f2bf(v.x); o[1] = f2bf(v.y); o[2] = f2bf(v.z); o[3] = f2bf(v.w);
    *(us4*)(d + i) = o;
  }
}

// mask * log2e -> bf16 in FRAGMENT order: mf[par][qg(64)][tt(32)][lg(4)][lr(16)][nf*4+i]
// total slots = 2*64*32*4*16 = 262144; each thread writes 16 bf16 (32 B).
__global__ void k_mcvt(const float* __restrict__ mask, unsigned short* __restrict__ mf){
  int idx = blockIdx.x*256 + threadIdx.x;
  if (idx >= 262144) return;
  int lr = idx & 15, lg = (idx >> 4) & 3, tt = (idx >> 6) & 31;
  int qg = (idx >> 11) & 63, par = idx >> 17;
  const float LOG2E = 1.4426950408889634f;
  const float* src = mask + (size_t)par*4194304 + 2097152;
  unsigned short o[16];
  #pragma unroll
  for (int nf=0; nf<4; ++nf)
    #pragma unroll
    for (int i=0; i<4; ++i){
      int q = qg*16 + lg*4 + i;
      int t = tt*64 + nf*16 + lr;
      o[nf*4+i] = f2bf(src[(size_t)q*2048 + t] * LOG2E);
    }
  us8* dst = (us8*)(mf + (size_t)idx*16);
  dst[0] = *(const us8*)&o[0];
  dst[1] = *(const us8*)&o[8];
}

__global__ void k_cache(const float* __restrict__ kc, unsigned short* __restrict__ kf){
  int i = (blockIdx.x * blockDim.x + threadIdx.x) * 4;
  if (i >= B_*POS_*H_*D_) return;
  int b = i >> 21;
  int rem = i & ((1 << 21) - 1);
  size_t src = (size_t)b * (2*POS_*H_*D_) + rem;
  size_t dst = (size_t)b * (L_*H_*D_) + rem;
  float4 k4 = *(const float4*)(kc + src);
  us4 ko;
  ko[0]=f2bf(k4.x); ko[1]=f2bf(k4.y); ko[2]=f2bf(k4.z); ko[3]=f2bf(k4.w);
  *(us4*)(kf + dst) = ko;
}

__global__ void k_rope(const float* __restrict__ qkv, const float* __restrict__ cosb,
    const float* __restrict__ sinb, float* __restrict__ kout, float* __restrict__ vout,
    unsigned short* __restrict__ qb, unsigned short* __restrict__ kf)
{
  int idx = blockIdx.x*blockDim.x + threadIdx.x;
  int j  = idx & 63;
  int hh = (idx >> 6) & 15;
  int s  = (idx >> 10) & 1023;
  int b  = idx >> 20;
  int m  = b*S_ + s;
  float c  = cosb[(POS_ + s)*64 + j];
  float sn = sinb[(POS_ + s)*64 + j];
  size_t base = (size_t)m*NQKV + hh*D_ + j;
  float q1 = qkv[base],          q2 = qkv[base + 64];
  float k1 = qkv[base + HID],    k2 = qkv[base + HID + 64];
  float v1 = qkv[base + 2*HID],  v2 = qkv[base + 2*HID + 64];
  float qr = c*q1 - sn*q2, qi = sn*q1 + c*q2;
  float kr = c*k1 - sn*k2, ki = sn*k1 + c*k2;
  const float SCQ = 0.12751743232994544f;   // (1/sqrt(128)) * log2e, folded into Q
  size_t o = (size_t)m*HID + hh*D_ + j;
  kout[o] = kr; kout[o + 64] = ki;
  vout[o] = v1; vout[o + 64] = v2;
  qb[o] = f2bf(qr*SCQ); qb[o + 64] = f2bf(qi*SCQ);
  size_t fo = ((size_t)(b*L_ + POS_ + s)*H_ + hh)*D_ + j;
  kf[fo] = f2bf(kr); kf[fo + 64] = f2bf(ki);
}

// Build V^T globally: vt[b][h][d][t], bf16.
__global__ __launch_bounds__(256) void k_vtrans(const float* __restrict__ vc,
    const float* __restrict__ qkv, unsigned short* __restrict__ vt)
{
  __shared__ unsigned short T[64*130];
  int blk = blockIdx.x;
  int tt = blk & 31, h = (blk >> 5) & 15, b = blk >> 9;
  int t0 = tt * 64;
  int tid = threadIdx.x;
  int d0 = (tid & 31) * 4, tr = tid >> 5;
  #pragma unroll
  for (int pass=0; pass<8; ++pass){
    int t = tr + pass*8;
    int gt = t0 + t;
    float4 v4;
    if (gt < POS_){
      v4 = *(const float4*)(vc + (((size_t)(b*2*POS_ + gt))*H_ + h)*D_ + d0);
    } else {
      v4 = *(const float4*)(qkv + (size_t)(b*S_ + gt - POS_)*NQKV + 2*HID + h*D_ + d0);
    }
    us4 o; o[0]=f2bf(v4.x); o[1]=f2bf(v4.y); o[2]=f2bf(v4.z); o[3]=f2bf(v4.w);
    *(us4*)(&T[t*130 + d0]) = o;
  }
  __syncthreads();
  int d = tid >> 1, th = (tid & 1) * 32;
  uint4 buf4[4];
  unsigned short* buf = (unsigned short*)buf4;
  #pragma unroll
  for (int e=0;e<32;++e) buf[e] = T[(th+e)*130 + d];
  unsigned short* dst = vt + (((size_t)(b*H_ + h)*D_ + d)*L_) + t0 + th;
  #pragma unroll
  for (int c=0;c<4;++c) *(uint4*)(dst + c*8) = buf4[c];
}

__global__ __launch_bounds__(256) void k_gemm(const unsigned short* __restrict__ A,
    const unsigned short* __restrict__ Bm, const float* __restrict__ bias,
    float* __restrict__ C, int Md, int Nd, int Kd)
{
  __shared__ unsigned short As[128*64];
  __shared__ unsigned short Bs[128*64];
  const int tid = threadIdx.x;
  const int lane = tid & 63, w = tid >> 6;
  const int wr = w >> 1, wc = w & 1;
  const int lg = lane >> 4, lr = lane & 15;
  const int tiles_n = Nd >> 7;
  const int tm = blockIdx.x / tiles_n, tn = blockIdx.x % tiles_n;
  f32x4 acc[4][4];
  #pragma unroll
  for (int i=0;i<4;++i)
    #pragma unroll
    for (int j=0;j<4;++j){ f32x4 z = {0.f,0.f,0.f,0.f}; acc[i][j] = z; }

  for (int k0 = 0; k0 < Kd; k0 += 64){
    #pragma unroll
    for (int j=0;j<4;++j){
      int chunk = j*256 + w*64 + lane;
      int row = chunk >> 3, cc = chunk & 7;
      int ccs = cc ^ (row & 7);
      const unsigned short* ga = A  + (size_t)(tm*128 + row)*Kd + k0 + ccs*8;
      __builtin_amdgcn_global_load_lds((gp_t)ga,
          (lp_t)((char*)As + (j*256 + w*64)*16), 16, 0, 0);
      const unsigned short* gb = Bm + (size_t)(tn*128 + row)*Kd + k0 + ccs*8;
      __builtin_amdgcn_global_load_lds((gp_t)gb,
          (lp_t)((char*)Bs + (j*256 + w*64)*16), 16, 0, 0);
    }
    __syncthreads();
    #pragma unroll
    for (int ks=0; ks<2; ++ks){
      bf16x8 af[4], bf[4];
      #pragma unroll
      for (int mi=0;mi<4;++mi){
        int row = wr*64 + mi*16 + lr;
        int byte = (row*128 + ks*64 + lg*16) ^ ((row & 7) << 4);
        af[mi] = *(const bf16x8*)((const char*)As + byte);
      }
      #pragma unroll
      for (int ni=0;ni<4;++ni){
        int row = wc*64 + ni*16 + lr;
        int byte = (row*128 + ks*64 + lg*16) ^ ((row & 7) << 4);
        bf[ni] = *(const bf16x8*)((const char*)Bs + byte);
      }
      #pragma unroll
      for (int mi=0;mi<4;++mi)
        #pragma unroll
        for (int ni=0;ni<4;++ni)
          acc[mi][ni] = __builtin_amdgcn_mfma_f32_16x16x32_bf16(af[mi], bf[ni], acc[mi][ni], 0, 0, 0);
    }
    __syncthreads();
  }
  #pragma unroll
  for (int mi=0;mi<4;++mi)
    #pragma unroll
    for (int ni=0;ni<4;++ni){
      int col = tn*128 + wc*64 + ni*16 + lr;
      float bv = bias[col];
      #pragma unroll
      for (int i=0;i<4;++i){
        int row = tm*128 + wr*64 + mi*16 + lg*4 + i;
        C[(size_t)row*Nd + col] = acc[mi][ni][i] + bv;
      }
    }
}

// Flash attention, 32 q-rows per wave (2 fragment-columns): every K/V LDS read
// feeds 2 MFMAs -> per-q-row LDS traffic halved (LDS-BW-bound per R9 analysis).
__global__ __launch_bounds__(256, 2) void k_attn_part(const unsigned short* __restrict__ Q,
    const unsigned short* __restrict__ Kf, const unsigned short* __restrict__ vt,
    const unsigned short* __restrict__ mf, float* __restrict__ Opart, float* __restrict__ ml)
{
  __shared__ unsigned short Kt[64*128];     // [t][d] swizzled, 16 KB
  __shared__ unsigned short Vt[128*64];     // [d][t] swizzled, 16 KB
  __shared__ unsigned short Pw[4][32*64];   // per-wave P (32 q x 64 t), 16 KB
  const int tid = threadIdx.x;
  const int lane = tid & 63, w = tid >> 6;
  const int lg = lane >> 4, lr = lane & 15;
  // XCD-aware decode: 512 blocks, bid%8 = XCD; each XCD gets 8 whole
  // (split,b,h) groups (8 qblks each) -> per-XCD K/V working set 4 MB = L2.
  const int hw = blockIdx.x;
  const int xcd = hw & 7, slot = hw >> 3;
  const int g = xcd*8 + (slot >> 3);         // 0..63
  const int qblk = slot & 7;                 // 0..7, 128 q-rows each
  const int h = g & 15, b = (g >> 4) & 1, split = g >> 5;
  const int q0 = qblk * 128;
  const int tlo = split * (L_/2);

  bf16x8 qf[2][4];
  #pragma unroll
  for (int qh=0; qh<2; ++qh){
    const unsigned short* qbase = Q + ((size_t)(b*S_ + q0 + w*32 + qh*16 + lr))*HID + h*D_;
    #pragma unroll
    for (int ks=0; ks<4; ++ks)
      qf[qh][ks] = *(const bf16x8*)(qbase + ks*32 + lg*8);
  }
  f32x4 oacc[2][8];
  #pragma unroll
  for (int qh=0; qh<2; ++qh)
    #pragma unroll
    for (int i=0;i<8;++i){ f32x4 z = {0.f,0.f,0.f,0.f}; oacc[qh][i] = z; }
  float m_i[2][4], l_i[2][4];
  #pragma unroll
  for (int qh=0; qh<2; ++qh)
    #pragma unroll
    for (int i=0;i<4;++i){ m_i[qh][i] = -1e30f; l_i[qh][i] = 0.f; }
  const unsigned short* vtb = vt + ((size_t)(b*H_ + h)*D_)*L_;
  // fragment-ordered mask: qg = q0/16 + w*2 + qh
  const unsigned short* mfrag[2];
  #pragma unroll
  for (int qh=0; qh<2; ++qh)
    mfrag[qh] = mf + ((size_t)((h & 1)*64 + qblk*8 + w*2 + qh) * 32) * 1024
                   + (size_t)(lg*16 + lr) * 16;

  for (int tof = 0; tof < L_/2; tof += 64){
    int t0 = tlo + tof;
    // stage K tile [64][128]
    #pragma unroll
    for (int j=0;j<4;++j){
      int chunk = j*256 + w*64 + lane;
      int row = chunk >> 4, cc = chunk & 15;
      int ccs = cc ^ (row & 7);
      const unsigned short* gk = Kf + ((size_t)(b*L_ + t0 + row)*H_ + h)*D_ + ccs*8;
      __builtin_amdgcn_global_load_lds((gp_t)gk,
          (lp_t)((char*)Kt + (j*256 + w*64)*16), 16, 0, 0);
    }
    // stage V^T tile [128][64]
    #pragma unroll
    for (int j=0;j<4;++j){
      int chunk = j*256 + w*64 + lane;
      int row = chunk >> 3, cc = chunk & 7;
      int ccs = cc ^ (row & 7);
      const unsigned short* gv = vtb + (size_t)row*L_ + t0 + ccs*8;
      __builtin_amdgcn_global_load_lds((gp_t)gv,
          (lp_t)((char*)Vt + (j*256 + w*64)*16), 16, 0, 0);
    }
    // mask fragments: 2 x (2 x 16B) per lane
    union { us8 v[2]; unsigned short s[16]; } mu[2];
    #pragma unroll
    for (int qh=0; qh<2; ++qh){
      const us8* mv = (const us8*)(mfrag[qh] + (size_t)(tof >> 6)*1024 + (size_t)(split ? 16384 : 0));
      mu[qh].v[0] = mv[0]; mu[qh].v[1] = mv[1];
    }
    __syncthreads();

    // QK^T: kb read once, used by both q-halves
    f32x4 sc[2][4];
    #pragma unroll
    for (int qh=0; qh<2; ++qh)
      #pragma unroll
      for (int nf=0;nf<4;++nf){ f32x4 z = {0.f,0.f,0.f,0.f}; sc[qh][nf] = z; }
    #pragma unroll
    for (int nf=0;nf<4;++nf){
      #pragma unroll
      for (int ks=0;ks<4;++ks){
        int row = nf*16 + lr;
        int byte = (row*256 + ks*64 + lg*16) ^ ((row & 7) << 4);
        bf16x8 kb = *(const bf16x8*)((const char*)Kt + byte);
        sc[0][nf] = __builtin_amdgcn_mfma_f32_16x16x32_bf16(qf[0][ks], kb, sc[0][nf], 0, 0, 0);
        sc[1][nf] = __builtin_amdgcn_mfma_f32_16x16x32_bf16(qf[1][ks], kb, sc[1][nf], 0, 0, 0);
      }
    }

    // online softmax per q-half
    float pp[2][4][4];
    #pragma unroll
    for (int qh=0; qh<2; ++qh){
      float sv[4][4];
      float tmax[4] = {-1e30f,-1e30f,-1e30f,-1e30f};
      #pragma unroll
      for (int nf=0;nf<4;++nf)
        #pragma unroll
        for (int i=0;i<4;++i){
          float v = sc[qh][nf][i] + bf2f(mu[qh].s[nf*4+i]);
          sv[nf][i] = v;
          tmax[i] = fmaxf(tmax[i], v);
        }
      #pragma unroll
      for (int i=0;i<4;++i){
        tmax[i] = fmaxf(tmax[i], __shfl_xor(tmax[i], 1));
        tmax[i] = fmaxf(tmax[i], __shfl_xor(tmax[i], 2));
        tmax[i] = fmaxf(tmax[i], __shfl_xor(tmax[i], 4));
        tmax[i] = fmaxf(tmax[i], __shfl_xor(tmax[i], 8));
      }
      float corr[4];
      #pragma unroll
      for (int i=0;i<4;++i){
        float mn = fmaxf(m_i[qh][i], tmax[i]);
        corr[i] = __builtin_amdgcn_exp2f(m_i[qh][i] - mn);
        m_i[qh][i] = mn;
      }
      float rs[4] = {0.f,0.f,0.f,0.f};
      #pragma unroll
      for (int nf=0;nf<4;++nf)
        #pragma unroll
        for (int i=0;i<4;++i){
          float p = __builtin_amdgcn_exp2f(sv[nf][i] - m_i[qh][i]);
          pp[qh][nf][i] = p;
          rs[i] += p;
        }
      #pragma unroll
      for (int i=0;i<4;++i){
        rs[i] += __shfl_xor(rs[i], 1);
        rs[i] += __shfl_xor(rs[i], 2);
        rs[i] += __shfl_xor(rs[i], 4);
        rs[i] += __shfl_xor(rs[i], 8);
        l_i[qh][i] = l_i[qh][i]*corr[i] + rs[i];
      }
      #pragma unroll
      for (int df=0;df<8;++df)
        #pragma unroll
        for (int i=0;i<4;++i) oacc[qh][df][i] *= corr[i];
    }

    // P -> per-wave LDS (32 rows x 64 cols, swizzled)
    #pragma unroll
    for (int qh=0; qh<2; ++qh)
      #pragma unroll
      for (int nf=0;nf<4;++nf)
        #pragma unroll
        for (int i=0;i<4;++i){
          int row = qh*16 + lg*4 + i;
          int byte = (row*128 + nf*32 + lr*2) ^ ((row & 7) << 4);
          *(unsigned short*)((char*)(&Pw[w][0]) + byte) = f2bf(pp[qh][nf][i]);
        }
    __asm__ volatile("s_waitcnt lgkmcnt(0)" ::: "memory");

    // PV: vb read once, used by both q-halves
    bf16x8 pa[2][2];
    #pragma unroll
    for (int qh=0; qh<2; ++qh)
      #pragma unroll
      for (int ks2=0; ks2<2; ++ks2){
        int row = qh*16 + lr;
        int pbyte = (row*128 + ks2*64 + lg*16) ^ ((row & 7) << 4);
        pa[qh][ks2] = *(const bf16x8*)((const char*)(&Pw[w][0]) + pbyte);
      }
    #pragma unroll
    for (int ks2=0; ks2<2; ++ks2){
      #pragma unroll
      for (int df=0;df<8;++df){
        int vrow = df*16 + lr;
        int vbyte = (vrow*128 + ks2*64 + lg*16) ^ ((vrow & 7) << 4);
        bf16x8 vb = *(const bf16x8*)((const char*)Vt + vbyte);
        oacc[0][df] = __builtin_amdgcn_mfma_f32_16x16x32_bf16(pa[0][ks2], vb, oacc[0][df], 0, 0, 0);
        oacc[1][df] = __builtin_amdgcn_mfma_f32_16x16x32_bf16(pa[1][ks2], vb, oacc[1][df], 0, 0, 0);
      }
    }
    __syncthreads();
  }

  #pragma unroll
  for (int qh=0; qh<2; ++qh){
    size_t rbase = (size_t)(b*H_ + h)*S_ + q0 + w*32 + qh*16;
    size_t pbase = (size_t)split*(B_*H_*S_) + rbase;
    #pragma unroll
    for (int df=0;df<8;++df)
      #pragma unroll
      for (int i=0;i<4;++i)
        Opart[(pbase + lg*4 + i)*D_ + df*16 + lr] = oacc[qh][df][i];
    if (lr == 0){
      #pragma unroll
      for (int i=0;i<4;++i){
        size_t row = pbase + lg*4 + i;
        ml[row*2]     = m_i[qh][i];
        ml[row*2 + 1] = l_i[qh][i];
      }
    }
  }
}

// Combine 2 splits: out = (w0*O0 + w1*O1) / (w0*l0 + w1*l1), weights exp2(m - M).
__global__ void k_comb(const float* __restrict__ Opart, const float* __restrict__ ml,
                       unsigned short* __restrict__ Ob)
{
  const int NR = B_*H_*S_;   // 32768 rows
  int idx = blockIdx.x*256 + threadIdx.x;       // NR*32 threads, 4 elems each
  int r = idx >> 5, dq = (idx & 31) * 4;
  float m0 = ml[(size_t)r*2],          l0 = ml[(size_t)r*2 + 1];
  float m1 = ml[(size_t)(NR + r)*2],   l1 = ml[(size_t)(NR + r)*2 + 1];
  float M  = fmaxf(m0, m1);
  float w0 = __builtin_amdgcn_exp2f(m0 - M);
  float w1 = __builtin_amdgcn_exp2f(m1 - M);
  float inv = 1.0f / (w0*l0 + w1*l1);
  float4 o0 = *(const float4*)(Opart + (size_t)r*D_ + dq);
  float4 o1 = *(const float4*)(Opart + (size_t)(NR + r)*D_ + dq);
  int s = r & (S_-1), bh = r >> 10;
  int b = bh >> 4, h = bh & 15;
  size_t o = ((size_t)(b*S_ + s))*HID + h*D_ + dq;
  us4 w;
  w[0] = f2bf((w0*o0.x + w1*o1.x)*inv);
  w[1] = f2bf((w0*o0.y + w1*o1.y)*inv);
  w[2] = f2bf((w0*o0.z + w1*o1.z)*inv);
  w[3] = f2bf((w0*o0.w + w1*o1.w)*inv);
  *(us4*)(Ob + o) = w;
}

extern "C" void kernel_launch(void* const* d_in, const int* in_sizes, int n_in,
                              void* d_out, int out_size, void* d_ws, size_t ws_size,
                              hipStream_t stream){
  const float* x    = (const float*)d_in[0];
  const float* mask = (const float*)d_in[1];
  const float* cosb = (const float*)d_in[2];
  const float* sinb = (const float*)d_in[3];
  const float* kc   = (const float*)d_in[4];
  const float* vc   = (const float*)d_in[5];
  const float* Wq   = (const float*)d_in[8];
  const float* bq   = (const float*)d_in[9];
  const float* Wk   = (const float*)d_in[10];
  const float* bk   = (const float*)d_in[11];
  const float* Wv   = (const float*)d_in[12];
  const float* bv   = (const float*)d_in[13];
  const float* Wo   = (const float*)d_in[14];
  const float* bo   = (const float*)d_in[15];

  float* out  = (float*)d_out;
  float* kout = out + 4194304;
  float* vout = out + 8388608;

  char* ws = (char*)d_ws;
  float*          qkv   = (float*)(ws);                      // 50331648 B (dead after rope/vtrans)
  float*          Opart = (float*)(ws);                      // 33554432 B, overlays dead qkv
  float*          ml    = (float*)(ws + 33554432);           // 524288 B
  unsigned short* xb    = (unsigned short*)(ws + 50331648);  // 8388608
  unsigned short* Wqkvb = (unsigned short*)(ws + 58720256);  // 25165824 (dead after QKV GEMM)
  unsigned short* mf    = (unsigned short*)(ws + 58720256);  // 8388608, overlays Wqkvb
  unsigned short* Wob   = (unsigned short*)(ws + 83886080);  // 8388608
  float*          bqkv  = (float*)(ws + 92274688);           // 24576
  unsigned short* qb    = (unsigned short*)(ws + 92299264);  // 8388608
  unsigned short* kf    = (unsigned short*)(ws + 100687872); // 16777216
  unsigned short* vt    = (unsigned short*)(ws + 117465088); // 16777216
  unsigned short* attnb = (unsigned short*)(ws + 134242304); // 8388608

  hipMemcpyAsync(bqkv,        bq, 2048*sizeof(float), hipMemcpyDeviceToDevice, stream);
  hipMemcpyAsync(bqkv + 2048, bk, 2048*sizeof(float), hipMemcpyDeviceToDevice, stream);
  hipMemcpyAsync(bqkv + 4096, bv, 2048*sizeof(float), hipMemcpyDeviceToDevice, stream);

  k_cvt<<<4096, 256, 0, stream>>>(x,  xb, 4194304);
  k_cvt<<<4096, 256, 0, stream>>>(Wq, Wqkvb,            4194304);
  k_cvt<<<4096, 256, 0, stream>>>(Wk, Wqkvb + 4194304,  4194304);
  k_cvt<<<4096, 256, 0, stream>>>(Wv, Wqkvb + 8388608,  4194304);
  k_cvt<<<4096, 256, 0, stream>>>(Wo, Wob, 4194304);
  k_cache<<<4096, 256, 0, stream>>>(kc, kf);

  k_gemm<<<16*48, 256, 0, stream>>>(xb, Wqkvb, bqkv, qkv, 2048, 6144, 2048);
  k_mcvt<<<1024, 256, 0, stream>>>(mask, mf);
  k_rope<<<8192, 256, 0, stream>>>(qkv, cosb, sinb, kout, vout, qb, kf);
  k_vtrans<<<1024, 256, 0, stream>>>(vc, qkv, vt);
  k_attn_part<<<512, 256, 0, stream>>>(qb, kf, vt, mf, Opart, ml);
  k_comb<<<4096, 256, 0, stream>>>(Opart, ml, attnb);
  k_gemm<<<16*16, 256, 0, stream>>>(attnb, Wob, bo, out, 2048, 2048, 2048);

  (void)in_sizes; (void)n_in; (void)out_size; (void)ws_size;
}

// Round 11
// 265.839 us; speedup vs baseline: 1.2874x; 1.0338x over previous
//
#include <hip/hip_runtime.h>
#include <hip/hip_bf16.h>
#include <stdint.h>

#define B_ 2
#define S_ 1024
#define H_ 16
#define D_ 128
#define HID 2048
#define POS_ 1024
#define L_ 2048
#define NQKV 6144

using f32x4  = __attribute__((ext_vector_type(4))) float;
using bf16x8 = __attribute__((ext_vector_type(8))) short;
using us4    = __attribute__((ext_vector_type(4))) unsigned short;
using us8    = __attribute__((ext_vector_type(8))) unsigned short;

typedef const __attribute__((address_space(1))) void* gp_t;
typedef __attribute__((address_space(3))) void* lp_t;

__device__ __forceinline__ unsigned short f2bf(float f){
  union { __hip_bfloat16 h; unsigned short u; } cv;
  cv.h = __float2bfloat16(f);            // HW cvt (m240: scalar cast compiles well)
  return cv.u;
}
__device__ __forceinline__ float bf2f(unsigned short u){
  return __uint_as_float(((uint32_t)u) << 16);
}

__global__ void k_cvt(const float* __restrict__ s, unsigned short* __restrict__ d, int n){
  int i = (blockIdx.x * blockDim.x + threadIdx.x) * 4;
  if (i < n){
    float4 v = *(const float4*)(s + i);
    us4 o;
    o[0] = f2bf(v.x); o[1] = f2bf(v.y); o[2] = f2bf(v.z); o[3] = f2bf(v.w);
    *(us4*)(d + i) = o;
  }
}

// fused Wq/Wk/Wv/Wo conversion: 4 x 4194304 elems, one launch
__global__ void k_cvt4(const float* __restrict__ a, const float* __restrict__ b2,
                       const float* __restrict__ c, const float* __restrict__ d,
                       unsigned short* __restrict__ o1, unsigned short* __restrict__ o2){
  int blk = blockIdx.x;
  int which = blk >> 12;
  int i = ((blk & 4095)*256 + threadIdx.x)*4;
  const float* src = which==0 ? a : which==1 ? b2 : which==2 ? c : d;
  unsigned short* dst = which==0 ? o1 : which==1 ? o1+4194304 : which==2 ? o1+8388608 : o2;
  float4 v = *(const float4*)(src + i);
  us4 o;
  o[0] = f2bf(v.x); o[1] = f2bf(v.y); o[2] = f2bf(v.z); o[3] = f2bf(v.w);
  *(us4*)(dst + i) = o;
}

// mask * log2e -> bf16 in FRAGMENT order: mf[par][qg(64)][tt(32)][lg(4)][lr(16)][nf*4+i]
__global__ void k_mcvt(const float* __restrict__ mask, unsigned short* __restrict__ mf){
  int idx = blockIdx.x*256 + threadIdx.x;
  if (idx >= 262144) return;
  int lr = idx & 15, lg = (idx >> 4) & 3, tt = (idx >> 6) & 31;
  int qg = (idx >> 11) & 63, par = idx >> 17;
  const float LOG2E = 1.4426950408889634f;
  const float* src = mask + (size_t)par*4194304 + 2097152;
  unsigned short o[16];
  #pragma unroll
  for (int nf=0; nf<4; ++nf)
    #pragma unroll
    for (int i=0; i<4; ++i){
      int q = qg*16 + lg*4 + i;
      int t = tt*64 + nf*16 + lr;
      o[nf*4+i] = f2bf(src[(size_t)q*2048 + t] * LOG2E);
    }
  us8* dst = (us8*)(mf + (size_t)idx*16);
  dst[0] = *(const us8*)&o[0];
  dst[1] = *(const us8*)&o[8];
}

__global__ void k_cache(const float* __restrict__ kc, unsigned short* __restrict__ kf){
  int i = (blockIdx.x * blockDim.x + threadIdx.x) * 4;
  if (i >= B_*POS_*H_*D_) return;
  int b = i >> 21;
  int rem = i & ((1 << 21) - 1);
  size_t src = (size_t)b * (2*POS_*H_*D_) + rem;
  size_t dst = (size_t)b * (L_*H_*D_) + rem;
  float4 k4 = *(const float4*)(kc + src);
  us4 ko;
  ko[0]=f2bf(k4.x); ko[1]=f2bf(k4.y); ko[2]=f2bf(k4.z); ko[3]=f2bf(k4.w);
  *(us4*)(kf + dst) = ko;
}

// rope reads bf16 qkv intermediate
__global__ void k_rope(const unsigned short* __restrict__ qkvb, const float* __restrict__ cosb,
    const float* __restrict__ sinb, float* __restrict__ kout, float* __restrict__ vout,
    unsigned short* __restrict__ qb, unsigned short* __restrict__ kf)
{
  int idx = blockIdx.x*blockDim.x + threadIdx.x;
  int j  = idx & 63;
  int hh = (idx >> 6) & 15;
  int s  = (idx >> 10) & 1023;
  int b  = idx >> 20;
  int m  = b*S_ + s;
  float c  = cosb[(POS_ + s)*64 + j];
  float sn = sinb[(POS_ + s)*64 + j];
  size_t base = (size_t)m*NQKV + hh*D_ + j;
  float q1 = bf2f(qkvb[base]),          q2 = bf2f(qkvb[base + 64]);
  float k1 = bf2f(qkvb[base + HID]),    k2 = bf2f(qkvb[base + HID + 64]);
  float v1 = bf2f(qkvb[base + 2*HID]),  v2 = bf2f(qkvb[base + 2*HID + 64]);
  float qr = c*q1 - sn*q2, qi = sn*q1 + c*q2;
  float kr = c*k1 - sn*k2, ki = sn*k1 + c*k2;
  const float SCQ = 0.12751743232994544f;   // (1/sqrt(128)) * log2e, folded into Q
  size_t o = (size_t)m*HID + hh*D_ + j;
  kout[o] = kr; kout[o + 64] = ki;
  vout[o] = v1; vout[o + 64] = v2;
  qb[o] = f2bf(qr*SCQ); qb[o + 64] = f2bf(qi*SCQ);
  size_t fo = ((size_t)(b*L_ + POS_ + s)*H_ + hh)*D_ + j;
  kf[fo] = f2bf(kr); kf[fo + 64] = f2bf(ki);
}

// Build V^T globally: vt[b][h][d][t], bf16.
__global__ __launch_bounds__(256) void k_vtrans(const float* __restrict__ vc,
    const unsigned short* __restrict__ qkvb, unsigned short* __restrict__ vt)
{
  __shared__ unsigned short T[64*130];
  int blk = blockIdx.x;
  int tt = blk & 31, h = (blk >> 5) & 15, b = blk >> 9;
  int t0 = tt * 64;
  int tid = threadIdx.x;
  int d0 = (tid & 31) * 4, tr = tid >> 5;
  #pragma unroll
  for (int pass=0; pass<8; ++pass){
    int t = tr + pass*8;
    int gt = t0 + t;
    us4 o;
    if (gt < POS_){
      float4 v4 = *(const float4*)(vc + (((size_t)(b*2*POS_ + gt))*H_ + h)*D_ + d0);
      o[0]=f2bf(v4.x); o[1]=f2bf(v4.y); o[2]=f2bf(v4.z); o[3]=f2bf(v4.w);
    } else {
      o = *(const us4*)(qkvb + (size_t)(b*S_ + gt - POS_)*NQKV + 2*HID + h*D_ + d0);
    }
    *(us4*)(&T[t*130 + d0]) = o;
  }
  __syncthreads();
  int d = tid >> 1, th = (tid & 1) * 32;
  uint4 buf4[4];
  unsigned short* buf = (unsigned short*)buf4;
  #pragma unroll
  for (int e=0;e<32;++e) buf[e] = T[(th+e)*130 + d];
  unsigned short* dst = vt + (((size_t)(b*H_ + h)*D_ + d)*L_) + t0 + th;
  #pragma unroll
  for (int c=0;c<4;++c) *(uint4*)(dst + c*8) = buf4[c];
}

__global__ __launch_bounds__(256) void k_gemm(const unsigned short* __restrict__ A,
    const unsigned short* __restrict__ Bm, const float* __restrict__ bias,
    void* __restrict__ Cout, int bf16out, int Md, int Nd, int Kd)
{
  __shared__ unsigned short As[128*64];
  __shared__ unsigned short Bs[128*64];
  const int tid = threadIdx.x;
  const int lane = tid & 63, w = tid >> 6;
  const int wr = w >> 1, wc = w & 1;
  const int lg = lane >> 4, lr = lane & 15;
  const int tiles_n = Nd >> 7;
  const int tm = blockIdx.x / tiles_n, tn = blockIdx.x % tiles_n;
  f32x4 acc[4][4];
  #pragma unroll
  for (int i=0;i<4;++i)
    #pragma unroll
    for (int j=0;j<4;++j){ f32x4 z = {0.f,0.f,0.f,0.f}; acc[i][j] = z; }

  for (int k0 = 0; k0 < Kd; k0 += 64){
    #pragma unroll
    for (int j=0;j<4;++j){
      int chunk = j*256 + w*64 + lane;
      int row = chunk >> 3, cc = chunk & 7;
      int ccs = cc ^ (row & 7);
      const unsigned short* ga = A  + (size_t)(tm*128 + row)*Kd + k0 + ccs*8;
      __builtin_amdgcn_global_load_lds((gp_t)ga,
          (lp_t)((char*)As + (j*256 + w*64)*16), 16, 0, 0);
      const unsigned short* gb = Bm + (size_t)(tn*128 + row)*Kd + k0 + ccs*8;
      __builtin_amdgcn_global_load_lds((gp_t)gb,
          (lp_t)((char*)Bs + (j*256 + w*64)*16), 16, 0, 0);
    }
    __syncthreads();
    #pragma unroll
    for (int ks=0; ks<2; ++ks){
      bf16x8 af[4], bf[4];
      #pragma unroll
      for (int mi=0;mi<4;++mi){
        int row = wr*64 + mi*16 + lr;
        int byte = (row*128 + ks*64 + lg*16) ^ ((row & 7) << 4);
        af[mi] = *(const bf16x8*)((const char*)As + byte);
      }
      #pragma unroll
      for (int ni=0;ni<4;++ni){
        int row = wc*64 + ni*16 + lr;
        int byte = (row*128 + ks*64 + lg*16) ^ ((row & 7) << 4);
        bf[ni] = *(const bf16x8*)((const char*)Bs + byte);
      }
      #pragma unroll
      for (int mi=0;mi<4;++mi)
        #pragma unroll
        for (int ni=0;ni<4;++ni)
          acc[mi][ni] = __builtin_amdgcn_mfma_f32_16x16x32_bf16(af[mi], bf[ni], acc[mi][ni], 0, 0, 0);
    }
    __syncthreads();
  }
  #pragma unroll
  for (int mi=0;mi<4;++mi)
    #pragma unroll
    for (int ni=0;ni<4;++ni){
      int col = tn*128 + wc*64 + ni*16 + lr;
      float bv = bias[col];
      #pragma unroll
      for (int i=0;i<4;++i){
        int row = tm*128 + wr*64 + mi*16 + lg*4 + i;
        float v = acc[mi][ni][i] + bv;
        if (bf16out) ((unsigned short*)Cout)[(size_t)row*Nd + col] = f2bf(v);
        else         ((float*)Cout)[(size_t)row*Nd + col] = v;
      }
    }
}

// Flash attention, 32 q-rows per wave; HW bf16 cvt + exact defer-rescale.
__global__ __launch_bounds__(256, 2) void k_attn_part(const unsigned short* __restrict__ Q,
    const unsigned short* __restrict__ Kf, const unsigned short* __restrict__ vt,
    const unsigned short* __restrict__ mf, float* __restrict__ Opart, float* __restrict__ ml)
{
  __shared__ unsigned short Kt[64*128];     // [t][d] swizzled, 16 KB
  __shared__ unsigned short Vt[128*64];     // [d][t] swizzled, 16 KB
  __shared__ unsigned short Pw[4][32*64];   // per-wave P (32 q x 64 t), 16 KB
  const int tid = threadIdx.x;
  const int lane = tid & 63, w = tid >> 6;
  const int lg = lane >> 4, lr = lane & 15;
  const int hw = blockIdx.x;
  const int xcd = hw & 7, slot = hw >> 3;
  const int g = xcd*8 + (slot >> 3);
  const int qblk = slot & 7;
  const int h = g & 15, b = (g >> 4) & 1, split = g >> 5;
  const int q0 = qblk * 128;
  const int tlo = split * (L_/2);

  bf16x8 qf[2][4];
  #pragma unroll
  for (int qh=0; qh<2; ++qh){
    const unsigned short* qbase = Q + ((size_t)(b*S_ + q0 + w*32 + qh*16 + lr))*HID + h*D_;
    #pragma unroll
    for (int ks=0; ks<4; ++ks)
      qf[qh][ks] = *(const bf16x8*)(qbase + ks*32 + lg*8);
  }
  f32x4 oacc[2][8];
  #pragma unroll
  for (int qh=0; qh<2; ++qh)
    #pragma unroll
    for (int i=0;i<8;++i){ f32x4 z = {0.f,0.f,0.f,0.f}; oacc[qh][i] = z; }
  float m_i[2][4], l_i[2][4];
  #pragma unroll
  for (int qh=0; qh<2; ++qh)
    #pragma unroll
    for (int i=0;i<4;++i){ m_i[qh][i] = -1e30f; l_i[qh][i] = 0.f; }
  const unsigned short* vtb = vt + ((size_t)(b*H_ + h)*D_)*L_;
  const unsigned short* mfrag[2];
  #pragma unroll
  for (int qh=0; qh<2; ++qh)
    mfrag[qh] = mf + ((size_t)((h & 1)*64 + qblk*8 + w*2 + qh) * 32) * 1024
                   + (size_t)(lg*16 + lr) * 16;

  for (int tof = 0; tof < L_/2; tof += 64){
    int t0 = tlo + tof;
    #pragma unroll
    for (int j=0;j<4;++j){
      int chunk = j*256 + w*64 + lane;
      int row = chunk >> 4, cc = chunk & 15;
      int ccs = cc ^ (row & 7);
      const unsigned short* gk = Kf + ((size_t)(b*L_ + t0 + row)*H_ + h)*D_ + ccs*8;
      __builtin_amdgcn_global_load_lds((gp_t)gk,
          (lp_t)((char*)Kt + (j*256 + w*64)*16), 16, 0, 0);
    }
    #pragma unroll
    for (int j=0;j<4;++j){
      int chunk = j*256 + w*64 + lane;
      int row = chunk >> 3, cc = chunk & 7;
      int ccs = cc ^ (row & 7);
      const unsigned short* gv = vtb + (size_t)row*L_ + t0 + ccs*8;
      __builtin_amdgcn_global_load_lds((gp_t)gv,
          (lp_t)((char*)Vt + (j*256 + w*64)*16), 16, 0, 0);
    }
    union { us8 v[2]; unsigned short s[16]; } mu[2];
    #pragma unroll
    for (int qh=0; qh<2; ++qh){
      const us8* mv = (const us8*)(mfrag[qh] + (size_t)(tof >> 6)*1024 + (size_t)(split ? 16384 : 0));
      mu[qh].v[0] = mv[0]; mu[qh].v[1] = mv[1];
    }
    __syncthreads();

    f32x4 sc[2][4];
    #pragma unroll
    for (int qh=0; qh<2; ++qh)
      #pragma unroll
      for (int nf=0;nf<4;++nf){ f32x4 z = {0.f,0.f,0.f,0.f}; sc[qh][nf] = z; }
    #pragma unroll
    for (int nf=0;nf<4;++nf){
      #pragma unroll
      for (int ks=0;ks<4;++ks){
        int row = nf*16 + lr;
        int byte = (row*256 + ks*64 + lg*16) ^ ((row & 7) << 4);
        bf16x8 kb = *(const bf16x8*)((const char*)Kt + byte);
        sc[0][nf] = __builtin_amdgcn_mfma_f32_16x16x32_bf16(qf[0][ks], kb, sc[0][nf], 0, 0, 0);
        sc[1][nf] = __builtin_amdgcn_mfma_f32_16x16x32_bf16(qf[1][ks], kb, sc[1][nf], 0, 0, 0);
      }
    }

    // mask add + per-row tile max
    float sv[2][4][4];
    float tmax[2][4];
    #pragma unroll
    for (int qh=0; qh<2; ++qh){
      #pragma unroll
      for (int i=0;i<4;++i) tmax[qh][i] = -1e30f;
      #pragma unroll
      for (int nf=0;nf<4;++nf)
        #pragma unroll
        for (int i=0;i<4;++i){
          float v = sc[qh][nf][i] + bf2f(mu[qh].s[nf*4+i]);
          sv[qh][nf][i] = v;
          tmax[qh][i] = fmaxf(tmax[qh][i], v);
        }
      #pragma unroll
      for (int i=0;i<4;++i){
        tmax[qh][i] = fmaxf(tmax[qh][i], __shfl_xor(tmax[qh][i], 1));
        tmax[qh][i] = fmaxf(tmax[qh][i], __shfl_xor(tmax[qh][i], 2));
        tmax[qh][i] = fmaxf(tmax[qh][i], __shfl_xor(tmax[qh][i], 4));
        tmax[qh][i] = fmaxf(tmax[qh][i], __shfl_xor(tmax[qh][i], 8));
      }
    }

    // exact defer-rescale: if no row grew, corr == 1 exactly -> skip rescale
    float corr[2][4];
    bool grow = false;
    #pragma unroll
    for (int qh=0; qh<2; ++qh)
      #pragma unroll
      for (int i=0;i<4;++i) grow = grow || (tmax[qh][i] > m_i[qh][i]);
    if (__any(grow)){
      #pragma unroll
      for (int qh=0; qh<2; ++qh)
        #pragma unroll
        for (int i=0;i<4;++i){
          float mn = fmaxf(m_i[qh][i], tmax[qh][i]);
          corr[qh][i] = __builtin_amdgcn_exp2f(m_i[qh][i] - mn);
          m_i[qh][i] = mn;
        }
      #pragma unroll
      for (int qh=0; qh<2; ++qh)
        #pragma unroll
        for (int df=0;df<8;++df)
          #pragma unroll
          for (int i=0;i<4;++i) oacc[qh][df][i] *= corr[qh][i];
    } else {
      #pragma unroll
      for (int qh=0; qh<2; ++qh)
        #pragma unroll
        for (int i=0;i<4;++i) corr[qh][i] = 1.0f;
    }

    // P = exp2(sv - m), row-sum, pack to LDS
    #pragma unroll
    for (int qh=0; qh<2; ++qh){
      float rs[4] = {0.f,0.f,0.f,0.f};
      #pragma unroll
      for (int nf=0;nf<4;++nf)
        #pragma unroll
        for (int i=0;i<4;++i){
          float p = __builtin_amdgcn_exp2f(sv[qh][nf][i] - m_i[qh][i]);
          rs[i] += p;
          int row = qh*16 + lg*4 + i;
          int byte = (row*128 + nf*32 + lr*2) ^ ((row & 7) << 4);
          *(unsigned short*)((char*)(&Pw[w][0]) + byte) = f2bf(p);
        }
      #pragma unroll
      for (int i=0;i<4;++i){
        rs[i] += __shfl_xor(rs[i], 1);
        rs[i] += __shfl_xor(rs[i], 2);
        rs[i] += __shfl_xor(rs[i], 4);
        rs[i] += __shfl_xor(rs[i], 8);
        l_i[qh][i] = l_i[qh][i]*corr[qh][i] + rs[i];
      }
    }
    __asm__ volatile("s_waitcnt lgkmcnt(0)" ::: "memory");

    bf16x8 pa[2][2];
    #pragma unroll
    for (int qh=0; qh<2; ++qh)
      #pragma unroll
      for (int ks2=0; ks2<2; ++ks2){
        int row = qh*16 + lr;
        int pbyte = (row*128 + ks2*64 + lg*16) ^ ((row & 7) << 4);
        pa[qh][ks2] = *(const bf16x8*)((const char*)(&Pw[w][0]) + pbyte);
      }
    #pragma unroll
    for (int ks2=0; ks2<2; ++ks2){
      #pragma unroll
      for (int df=0;df<8;++df){
        int vrow = df*16 + lr;
        int vbyte = (vrow*128 + ks2*64 + lg*16) ^ ((vrow & 7) << 4);
        bf16x8 vb = *(const bf16x8*)((const char*)Vt + vbyte);
        oacc[0][df] = __builtin_amdgcn_mfma_f32_16x16x32_bf16(pa[0][ks2], vb, oacc[0][df], 0, 0, 0);
        oacc[1][df] = __builtin_amdgcn_mfma_f32_16x16x32_bf16(pa[1][ks2], vb, oacc[1][df], 0, 0, 0);
      }
    }
    __syncthreads();
  }

  #pragma unroll
  for (int qh=0; qh<2; ++qh){
    size_t rbase = (size_t)(b*H_ + h)*S_ + q0 + w*32 + qh*16;
    size_t pbase = (size_t)split*(B_*H_*S_) + rbase;
    #pragma unroll
    for (int df=0;df<8;++df)
      #pragma unroll
      for (int i=0;i<4;++i)
        Opart[(pbase + lg*4 + i)*D_ + df*16 + lr] = oacc[qh][df][i];
    if (lr == 0){
      #pragma unroll
      for (int i=0;i<4;++i){
        size_t row = pbase + lg*4 + i;
        ml[row*2]     = m_i[qh][i];
        ml[row*2 + 1] = l_i[qh][i];
      }
    }
  }
}

// Combine 2 splits.
__global__ void k_comb(const float* __restrict__ Opart, const float* __restrict__ ml,
                       unsigned short* __restrict__ Ob)
{
  const int NR = B_*H_*S_;
  int idx = blockIdx.x*256 + threadIdx.x;
  int r = idx >> 5, dq = (idx & 31) * 4;
  float m0 = ml[(size_t)r*2],          l0 = ml[(size_t)r*2 + 1];
  float m1 = ml[(size_t)(NR + r)*2],   l1 = ml[(size_t)(NR + r)*2 + 1];
  float M  = fmaxf(m0, m1);
  float w0 = __builtin_amdgcn_exp2f(m0 - M);
  float w1 = __builtin_amdgcn_exp2f(m1 - M);
  float inv = 1.0f / (w0*l0 + w1*l1);
  float4 o0 = *(const float4*)(Opart + (size_t)r*D_ + dq);
  float4 o1 = *(const float4*)(Opart + (size_t)(NR + r)*D_ + dq);
  int s = r & (S_-1), bh = r >> 10;
  int b = bh >> 4, h = bh & 15;
  size_t o = ((size_t)(b*S_ + s))*HID + h*D_ + dq;
  us4 w;
  w[0] = f2bf((w0*o0.x + w1*o1.x)*inv);
  w[1] = f2bf((w0*o0.y + w1*o1.y)*inv);
  w[2] = f2bf((w0*o0.z + w1*o1.z)*inv);
  w[3] = f2bf((w0*o0.w + w1*o1.w)*inv);
  *(us4*)(Ob + o) = w;
}

extern "C" void kernel_launch(void* const* d_in, const int* in_sizes, int n_in,
                              void* d_out, int out_size, void* d_ws, size_t ws_size,
                              hipStream_t stream){
  const float* x    = (const float*)d_in[0];
  const float* mask = (const float*)d_in[1];
  const float* cosb = (const float*)d_in[2];
  const float* sinb = (const float*)d_in[3];
  const float* kc   = (const float*)d_in[4];
  const float* vc   = (const float*)d_in[5];
  const float* Wq   = (const float*)d_in[8];
  const float* bq   = (const float*)d_in[9];
  const float* Wk   = (const float*)d_in[10];
  const float* bk   = (const float*)d_in[11];
  const float* Wv   = (const float*)d_in[12];
  const float* bv   = (const float*)d_in[13];
  const float* Wo   = (const float*)d_in[14];
  const float* bo   = (const float*)d_in[15];

  float* out  = (float*)d_out;
  float* kout = out + 4194304;
  float* vout = out + 8388608;

  char* ws = (char*)d_ws;
  unsigned short* qkvb  = (unsigned short*)(ws);             // 25165824 B (dead after rope/vtrans)
  float*          Opart = (float*)(ws);                      // 33554432 B, overlays dead qkvb
  float*          ml    = (float*)(ws + 33554432);           // 524288 B
  unsigned short* xb    = (unsigned short*)(ws + 50331648);  // 8388608
  unsigned short* Wqkvb = (unsigned short*)(ws + 58720256);  // 25165824 (dead after QKV GEMM)
  unsigned short* mf    = (unsigned short*)(ws + 58720256);  // 8388608, overlays Wqkvb
  unsigned short* Wob   = (unsigned short*)(ws + 83886080);  // 8388608
  float*          bqkv  = (float*)(ws + 92274688);           // 24576
  unsigned short* qb    = (unsigned short*)(ws + 92299264);  // 8388608
  unsigned short* kf    = (unsigned short*)(ws + 100687872); // 16777216
  unsigned short* vt    = (unsigned short*)(ws + 117465088); // 16777216
  unsigned short* attnb = (unsigned short*)(ws + 134242304); // 8388608

  hipMemcpyAsync(bqkv,        bq, 2048*sizeof(float), hipMemcpyDeviceToDevice, stream);
  hipMemcpyAsync(bqkv + 2048, bk, 2048*sizeof(float), hipMemcpyDeviceToDevice, stream);
  hipMemcpyAsync(bqkv + 4096, bv, 2048*sizeof(float), hipMemcpyDeviceToDevice, stream);

  k_cvt<<<4096, 256, 0, stream>>>(x,  xb, 4194304);
  k_cvt4<<<16384, 256, 0, stream>>>(Wq, Wk, Wv, Wo, Wqkvb, Wob);
  k_cache<<<4096, 256, 0, stream>>>(kc, kf);

  k_gemm<<<16*48, 256, 0, stream>>>(xb, Wqkvb, bqkv, qkvb, 1, 2048, 6144, 2048);
  k_mcvt<<<1024, 256, 0, stream>>>(mask, mf);
  k_rope<<<8192, 256, 0, stream>>>(qkvb, cosb, sinb, kout, vout, qb, kf);
  k_vtrans<<<1024, 256, 0, stream>>>(vc, qkvb, vt);
  k_attn_part<<<512, 256, 0, stream>>>(qb, kf, vt, mf, Opart, ml);
  k_comb<<<4096, 256, 0, stream>>>(Opart, ml, attnb);
  k_gemm<<<16*16, 256, 0, stream>>>(attnb, Wob, bo, out, 0, 2048, 2048, 2048);

  (void)in_sizes; (void)n_in; (void)out_size; (void)ws_size;
}